// Round 9
// baseline (144.617 us; speedup 1.0000x reference)
//
#include <hip/hip_runtime.h>

// ---------------------------------------------------------------------------
// SelfAttentionBlock: GroupNorm(32,512) -> QKV(512x512) -> MHA(H=8,d=64,s=1024)
//                     -> out proj -> +residual.   b=8, x [8,512,32,32] fp32.
// v9: qkv GEMM moved to MX-scaled fp8 MFMA 16x16x128 (unit e8m0 scales ->
// numerically identical to non-scaled fp8, ~2x MFMA rate, half the barriers).
// BK=128, 16B-chunk XOR-by-(row&7) swizzle keeps b128 frag reads at 2-way
// (free). C/D layout is shape-determined -> epilogue identical to v8.
// gn / attention / out-proj unchanged from v8.
// ---------------------------------------------------------------------------

typedef __bf16 bf16x8 __attribute__((ext_vector_type(8)));
typedef __bf16 bf16x4 __attribute__((ext_vector_type(4)));
typedef float floatx4 __attribute__((ext_vector_type(4)));
typedef int intx8 __attribute__((ext_vector_type(8)));

static __device__ __forceinline__ floatx4 mfma_fp8(long a, long b, floatx4 c) {
  return __builtin_amdgcn_mfma_f32_16x16x32_fp8_fp8(a, b, c, 0, 0, 0);
}

// MX-scaled fp8 K=128, unit scales (e8m0 0x7F = 2^0). cbsz=0/blgp=0 -> e4m3.
static __device__ __forceinline__ floatx4 mfma_mx(intx8 a, intx8 b, floatx4 c) {
  return __builtin_amdgcn_mfma_scale_f32_16x16x128_f8f6f4(
      a, b, c, 0, 0, 0, 0x7F7F7F7F, 0, 0x7F7F7F7F);
}

// async global->LDS 16B DMA; LDS dest must be wave-uniform base + lane*16.
static __device__ __forceinline__ void async_cp16(const void* g, void* l) {
  __builtin_amdgcn_global_load_lds(
      (const __attribute__((address_space(1))) unsigned int*)g,
      (__attribute__((address_space(3))) unsigned int*)l, 16, 0, 0);
}

// 8 bf16 (uint4) -> 8 fp8 e4m3 (uint2)
static __device__ __forceinline__ uint2 cvt8_bf16_fp8(uint4 v) {
  union { uint4 u; __bf16 h[8]; } in; in.u = v;
  float f[8];
#pragma unroll
  for (int i = 0; i < 8; ++i) f[i] = (float)in.h[i];
  int lo = __builtin_amdgcn_cvt_pk_fp8_f32(f[0], f[1], 0, false);
  lo = __builtin_amdgcn_cvt_pk_fp8_f32(f[2], f[3], lo, true);
  int hi = __builtin_amdgcn_cvt_pk_fp8_f32(f[4], f[5], 0, false);
  hi = __builtin_amdgcn_cvt_pk_fp8_f32(f[6], f[7], hi, true);
  return uint2{(unsigned)lo, (unsigned)hi};
}

// 64B-row swizzle (v7/v8 GEMM-out + attn staging): 16B chunks XOR s(r)&3.
static __device__ __forceinline__ int swz_s(int r) {
  return (r & 3) ^ ((r >> 2) & 3);
}
static __device__ __forceinline__ int frag_addr(int row, int kh, int quad) {
  int chunk = (kh << 1) | (quad >> 1);
  return row * 64 + ((chunk ^ swz_s(row)) << 4) + ((quad & 1) << 3);
}

// ---------------------------------------------------------------------------
// Kernel 1: fused GroupNorm (blocks 0..255, single-pass) + weight prep
// (blocks 256..511). Unchanged from v8.
// ---------------------------------------------------------------------------
__global__ __launch_bounds__(256) void prep_gn_kernel(
    const float* __restrict__ x, const float* __restrict__ gamma,
    const float* __restrict__ beta,
    const float* __restrict__ Wq, const float* __restrict__ bq,
    const float* __restrict__ Wk, const float* __restrict__ bk,
    const float* __restrict__ Wv, const float* __restrict__ bv,
    const float* __restrict__ Wo,
    unsigned char* __restrict__ wqkv, unsigned char* __restrict__ wo,
    float* __restrict__ bqkv, unsigned char* __restrict__ t) {
  __shared__ __bf16 tile[16 * 1024];
  __shared__ float rbuf[8];
  int tid = threadIdx.x;
  int bx = blockIdx.x;

  if (bx >= 256) {
    int i = ((bx - 256) * 256 + tid) * 4;
    float4 q4 = *(const float4*)(Wq + i);
    float4 k4 = *(const float4*)(Wk + i);
    float4 v4 = *(const float4*)(Wv + i);
    float4 o4 = *(const float4*)(Wo + i);
    int p;
    p = __builtin_amdgcn_cvt_pk_fp8_f32(q4.x * 16.f, q4.y * 16.f, 0, false);
    p = __builtin_amdgcn_cvt_pk_fp8_f32(q4.z * 16.f, q4.w * 16.f, p, true);
    *(unsigned int*)(wqkv + i) = (unsigned)p;
    p = __builtin_amdgcn_cvt_pk_fp8_f32(k4.x * 16.f, k4.y * 16.f, 0, false);
    p = __builtin_amdgcn_cvt_pk_fp8_f32(k4.z * 16.f, k4.w * 16.f, p, true);
    *(unsigned int*)(wqkv + 262144 + i) = (unsigned)p;
    p = __builtin_amdgcn_cvt_pk_fp8_f32(v4.x * 16.f, v4.y * 16.f, 0, false);
    p = __builtin_amdgcn_cvt_pk_fp8_f32(v4.z * 16.f, v4.w * 16.f, p, true);
    *(unsigned int*)(wqkv + 524288 + i) = (unsigned)p;
    p = __builtin_amdgcn_cvt_pk_fp8_f32(o4.x * 16.f, o4.y * 16.f, 0, false);
    p = __builtin_amdgcn_cvt_pk_fp8_f32(o4.z * 16.f, o4.w * 16.f, p, true);
    *(unsigned int*)(wo + i) = (unsigned)p;
    int j = (bx - 256) * 256 + tid;
    if (j < 512) {
      bqkv[j]        = bq[j];
      bqkv[512 + j]  = bk[j];
      bqkv[1024 + j] = bv[j];
    }
    return;
  }

  int b = bx >> 5, g = bx & 31;
  const float4* xp4 = (const float4*)(x + (size_t)(b * 512 + g * 16) * 1024);

  float4 vreg[16];
  float sacc = 0.f, ssacc = 0.f;
#pragma unroll
  for (int it = 0; it < 16; ++it) {
    float4 v = xp4[it * 256 + tid];
    vreg[it] = v;
    sacc += v.x + v.y + v.z + v.w;
    ssacc += v.x * v.x + v.y * v.y + v.z * v.z + v.w * v.w;
  }
#pragma unroll
  for (int off = 1; off < 64; off <<= 1) {
    sacc += __shfl_xor(sacc, off);
    ssacc += __shfl_xor(ssacc, off);
  }
  int wv = tid >> 6;
  if ((tid & 63) == 0) { rbuf[wv] = sacc; rbuf[4 + wv] = ssacc; }
  __syncthreads();
  float S1 = rbuf[0] + rbuf[1] + rbuf[2] + rbuf[3];
  float S2 = rbuf[4] + rbuf[5] + rbuf[6] + rbuf[7];
  float mean = S1 * (1.f / 16384.f);
  float var = S2 * (1.f / 16384.f) - mean * mean;
  float inv = rsqrtf(var + 1e-5f);

#pragma unroll
  for (int it = 0; it < 16; ++it) {
    float4 v = vreg[it];
    float ga = gamma[g * 16 + it], be = beta[g * 16 + it];
    int base = it * 1024 + tid * 4;
    tile[base + 0] = (__bf16)((v.x - mean) * inv * ga + be);
    tile[base + 1] = (__bf16)((v.y - mean) * inv * ga + be);
    tile[base + 2] = (__bf16)((v.z - mean) * inv * ga + be);
    tile[base + 3] = (__bf16)((v.w - mean) * inv * ga + be);
  }
  __syncthreads();

#pragma unroll
  for (int j = 0; j < 8; ++j) {
    int qid = j * 256 + tid;
    int sidx = qid >> 1, half = qid & 1;
    union { uint4 u; __bf16 h[8]; } o;
#pragma unroll
    for (int i = 0; i < 8; ++i) o.h[i] = tile[(half * 8 + i) * 1024 + sidx];
    uint2 v8 = cvt8_bf16_fp8(o.u);
    *(uint2*)(t + (size_t)(b * 1024 + sidx) * 512 + g * 16 + half * 8) = v8;
  }
}

// ---------------------------------------------------------------------------
// Kernel 2: fused QKV GEMM, MX fp8 K=128. C[m,n] = t[m,:].wqkv[n,:]/16+bias.
// M=8192, N=1536, K=512. 128x128 tile, 4 waves of 64x64, BK=128 (4 K-steps),
// swizzled global_load_lds staging (128B rows, chunk ^= row&7).
// A/B frag: [m=l15][k=quad*32+j] -> 2 uint4 from LDS. C/D layout unchanged
// -> epilogue identical to v8 (fp8 q,k [b,h,s,d]; v^T [b,h,d,s]).
// ---------------------------------------------------------------------------
__global__ __launch_bounds__(256) void gemm_qkv_kernel(
    const unsigned char* __restrict__ t, const unsigned char* __restrict__ wqkv,
    const float* __restrict__ bqkv,
    unsigned char* __restrict__ qb, unsigned char* __restrict__ kb,
    unsigned char* __restrict__ vt) {
  __shared__ __align__(16) unsigned char smemraw[32768];  // As|Bs; epi ctile
  unsigned char* As = smemraw;
  unsigned char* Bs = smemraw + 16384;
  __bf16* ctile = (__bf16*)smemraw;    // 32 x 136 bf16 epilogue view
  int tid = threadIdx.x;
  int m0 = blockIdx.x * 128;
  int n0 = blockIdx.y * 128;
  int wave = tid >> 6, lane = tid & 63;
  int l15 = lane & 15, quad = lane >> 4;
  int wm = wave >> 1, wn = wave & 1;

  floatx4 acc[4][4];
#pragma unroll
  for (int mi = 0; mi < 4; ++mi)
#pragma unroll
    for (int ni = 0; ni < 4; ++ni) acc[mi][ni] = (floatx4){0.f, 0.f, 0.f, 0.f};

  // staging: 4 slots per matrix; slot -> row r = slot>>3, chunk-slot cs =
  // slot&7; global chunk c = cs ^ (r&7). 128B per row per K-step.
  const unsigned char* gA[4]; const unsigned char* gB[4];
  unsigned char *lA[4], *lB[4];
#pragma unroll
  for (int u = 0; u < 4; ++u) {
    int slot = u * 256 + tid;
    int r = slot >> 3, cs = slot & 7;
    int c = cs ^ (r & 7);
    gA[u] = t + (size_t)(m0 + r) * 512 + c * 16;
    gB[u] = wqkv + (size_t)(n0 + r) * 512 + c * 16;
    lA[u] = As + slot * 16;
    lB[u] = Bs + slot * 16;
  }

  int r7 = l15 & 7;
  int pc0 = (quad * 2) ^ r7;        // physical chunk of logical bytes [q*32, q*32+16)
  int pc1 = (quad * 2 + 1) ^ r7;    // physical chunk of logical bytes [q*32+16, ..+32)

  for (int k0 = 0; k0 < 512; k0 += 128) {
#pragma unroll
    for (int u = 0; u < 4; ++u) {
      async_cp16(gA[u] + k0, lA[u]);
      async_cp16(gB[u] + k0, lB[u]);
    }
    __syncthreads();
    intx8 af[4], bfr[4];
#pragma unroll
    for (int mi = 0; mi < 4; ++mi) {
      int row = wm * 64 + mi * 16 + l15;
      uint4 lo = *(const uint4*)&As[row * 128 + pc0 * 16];
      uint4 hi = *(const uint4*)&As[row * 128 + pc1 * 16];
      af[mi] = (intx8){(int)lo.x, (int)lo.y, (int)lo.z, (int)lo.w,
                       (int)hi.x, (int)hi.y, (int)hi.z, (int)hi.w};
    }
#pragma unroll
    for (int ni = 0; ni < 4; ++ni) {
      int row = wn * 64 + ni * 16 + l15;
      uint4 lo = *(const uint4*)&Bs[row * 128 + pc0 * 16];
      uint4 hi = *(const uint4*)&Bs[row * 128 + pc1 * 16];
      bfr[ni] = (intx8){(int)lo.x, (int)lo.y, (int)lo.z, (int)lo.w,
                        (int)hi.x, (int)hi.y, (int)hi.z, (int)hi.w};
    }
#pragma unroll
    for (int mi = 0; mi < 4; ++mi)
#pragma unroll
      for (int ni = 0; ni < 4; ++ni)
        acc[mi][ni] = mfma_mx(af[mi], bfr[ni], acc[mi][ni]);
    __syncthreads();
  }

  int mat = n0 >> 9;           // 0=q, 1=k, 2=v
  int bidx = m0 >> 10, s0 = m0 & 1023;
  int hA = (n0 & 511) >> 6;
  float bias[4];
#pragma unroll
  for (int ni = 0; ni < 4; ++ni)
    bias[ni] = bqkv[n0 + wn * 64 + ni * 16 + l15];

  if (mat < 2) {
    unsigned char* dst = (mat == 0) ? qb : kb;
    for (int c = 0; c < 4; ++c) {
      if ((c >> 1) == wm) {
#pragma unroll
        for (int mi2 = 0; mi2 < 2; ++mi2) {
          int mi = (c & 1) * 2 + mi2;
          int lrow = mi2 * 16 + quad * 4;
#pragma unroll
          for (int ni = 0; ni < 4; ++ni)
#pragma unroll
            for (int r = 0; r < 4; ++r)
              ctile[(lrow + r) * 136 + wn * 64 + ni * 16 + l15] =
                  (__bf16)(acc[mi][ni][r] * 0.0625f + bias[ni]);
        }
      }
      __syncthreads();
#pragma unroll
      for (int u = 0; u < 2; ++u) {
        int f = tid * 16 + u * 8;
        int row = f >> 7, col = f & 127;
        uint2 val = cvt8_bf16_fp8(*(uint4*)&ctile[row * 136 + col]);
        int head = hA + (col >> 6), d = col & 63;
        *(uint2*)(dst + ((size_t)(bidx * 8 + head) * 1024 + s0 + c * 32 + row) * 64 + d) = val;
      }
      __syncthreads();
    }
  } else {
    for (int c = 0; c < 4; ++c) {
      if ((c >> 1) == wn) {
#pragma unroll
        for (int ni2 = 0; ni2 < 2; ++ni2) {
          int ni = (c & 1) * 2 + ni2;
          int nrow = ni2 * 16 + l15;
#pragma unroll
          for (int mi = 0; mi < 4; ++mi)
#pragma unroll
            for (int r = 0; r < 4; ++r)
              ctile[nrow * 136 + wm * 64 + mi * 16 + quad * 4 + r] =
                  (__bf16)(acc[mi][ni][r] * 0.0625f + bias[ni]);
        }
      }
      __syncthreads();
#pragma unroll
      for (int u = 0; u < 2; ++u) {
        int f = tid * 16 + u * 8;
        int nrow = f >> 7, mcol = f & 127;
        uint2 val = cvt8_bf16_fp8(*(uint4*)&ctile[nrow * 136 + mcol]);
        int nloc = c * 32 + nrow;
        int head = hA + (nloc >> 6), d = nloc & 63;
        *(uint2*)(vt + ((size_t)(bidx * 8 + head) * 64 + d) * 1024 + s0 + mcol) = val;
      }
      __syncthreads();
    }
  }
}

// ---------------------------------------------------------------------------
// Kernel 3: flash attention (fp8 core). Unchanged from v8.
// ---------------------------------------------------------------------------
__global__ __launch_bounds__(256) void attn_kernel(
    const unsigned char* __restrict__ qb, const unsigned char* __restrict__ kb,
    const unsigned char* __restrict__ vt, unsigned char* __restrict__ ao) {
  __shared__ __align__(16) unsigned char Ks[2][64 * 80];
  __shared__ __align__(16) unsigned char Vs[2][64 * 80];
  __shared__ __align__(16) __bf16 Ps[128 * 72];   // fp8 P / bf16 O epilogue
  __shared__ float lbuf[128];
  unsigned char* Psb = (unsigned char*)Ps;
  const float SCL = 0.125f * 1.4426950408889634f;
  int tid = threadIdx.x;
  int bx = blockIdx.x;
  int b = bx >> 6, h = (bx >> 3) & 7, q128 = bx & 7;
  int wv = tid >> 6, lane = tid & 63, l15 = lane & 15, quad = lane >> 4;
  size_t bh = (size_t)(b * 8 + h) * 65536;
  const unsigned char* Qp = qb + bh;
  const unsigned char* Kp = kb + bh;
  const unsigned char* Vp = vt + bh;   // [d][s], row stride 1024 bytes
  int q0 = q128 * 128, qw = q0 + wv * 32;

  long aq[2][2];
#pragma unroll
  for (int mi = 0; mi < 2; ++mi)
#pragma unroll
    for (int kh = 0; kh < 2; ++kh)
      aq[mi][kh] = *(const long*)(Qp + (size_t)(qw + mi * 16 + l15) * 64 + kh * 32 + quad * 8);

  floatx4 oacc[2][4];
  float lsum[2] = {0.f, 0.f};          // partial l for q = l15 (+16*mi)
#pragma unroll
  for (int mi = 0; mi < 2; ++mi)
#pragma unroll
    for (int di = 0; di < 4; ++di) oacc[mi][di] = (floatx4){0.f, 0.f, 0.f, 0.f};

  int srow = tid >> 2, scol = (tid & 3) * 16;
  int ldsoff = srow * 80 + scol;

  uint4 kr, vr;
  kr = *(const uint4*)(Kp + (size_t)srow * 64 + scol);
  vr = *(const uint4*)(Vp + (size_t)srow * 1024 + scol);

  for (int kt = 0; kt < 16; ++kt) {
    int cur = kt & 1;
    *(uint4*)&Ks[cur][ldsoff] = kr;
    *(uint4*)&Vs[cur][ldsoff] = vr;
    if (kt < 15) {
      int nt = kt + 1;
      kr = *(const uint4*)(Kp + (size_t)(nt * 64 + srow) * 64 + scol);
      vr = *(const uint4*)(Vp + (size_t)srow * 1024 + nt * 64 + scol);
    }
    __syncthreads();

    floatx4 sa[2][4];
#pragma unroll
    for (int ni = 0; ni < 4; ++ni) {
      long bk0 = *(const long*)&Ks[cur][(ni * 16 + l15) * 80 + quad * 8];
      long bk1 = *(const long*)&Ks[cur][(ni * 16 + l15) * 80 + 32 + quad * 8];
#pragma unroll
      for (int mi = 0; mi < 2; ++mi) {
        floatx4 s4 = (floatx4){0.f, 0.f, 0.f, 0.f};
        s4 = mfma_fp8(bk0, aq[mi][0], s4);
        s4 = mfma_fp8(bk1, aq[mi][1], s4);
        sa[mi][ni] = s4;
      }
    }

#pragma unroll
    for (int mi = 0; mi < 2; ++mi)
#pragma unroll
      for (int ni = 0; ni < 4; ++ni) {
        float e0 = __builtin_amdgcn_exp2f(sa[mi][ni][0] * SCL);
        float e1 = __builtin_amdgcn_exp2f(sa[mi][ni][1] * SCL);
        float e2 = __builtin_amdgcn_exp2f(sa[mi][ni][2] * SCL);
        float e3 = __builtin_amdgcn_exp2f(sa[mi][ni][3] * SCL);
        lsum[mi] += (e0 + e1) + (e2 + e3);
        int pk = __builtin_amdgcn_cvt_pk_fp8_f32(e0, e1, 0, false);
        pk = __builtin_amdgcn_cvt_pk_fp8_f32(e2, e3, pk, true);
        *(unsigned int*)&Psb[(wv * 32 + mi * 16 + l15) * 72 + ni * 16 + quad * 4] =
            (unsigned)pk;
      }

    long ap[2][2];
#pragma unroll
    for (int mi = 0; mi < 2; ++mi) {
      ap[mi][0] = *(const long*)&Psb[(wv * 32 + mi * 16 + l15) * 72 + quad * 8];
      ap[mi][1] = *(const long*)&Psb[(wv * 32 + mi * 16 + l15) * 72 + 32 + quad * 8];
    }
#pragma unroll
    for (int di = 0; di < 4; ++di) {
      long bv0 = *(const long*)&Vs[cur][(di * 16 + l15) * 80 + quad * 8];
      long bv1 = *(const long*)&Vs[cur][(di * 16 + l15) * 80 + 32 + quad * 8];
#pragma unroll
      for (int mi = 0; mi < 2; ++mi) {
        oacc[mi][di] = mfma_fp8(ap[mi][0], bv0, oacc[mi][di]);
        oacc[mi][di] = mfma_fp8(ap[mi][1], bv1, oacc[mi][di]);
      }
    }
  }

  // finalize l: sum the 4 quad-lanes sharing l15, stash to lbuf, realign.
#pragma unroll
  for (int mi = 0; mi < 2; ++mi) {
    lsum[mi] += __shfl_xor(lsum[mi], 16);
    lsum[mi] += __shfl_xor(lsum[mi], 32);
  }
  __syncthreads();   // waves done with fp8 P before overwriting Ps as bf16
  if (quad == 0) {
    lbuf[wv * 32 + l15] = lsum[0];
    lbuf[wv * 32 + 16 + l15] = lsum[1];
  }
  __syncthreads();

  // epilogue: O*16/l -> Ps (bf16 [128][72]) -> fp8 coalesced stores
#pragma unroll
  for (int mi = 0; mi < 2; ++mi)
#pragma unroll
    for (int r = 0; r < 4; ++r) {
      float invl = 16.f / lbuf[wv * 32 + mi * 16 + quad * 4 + r];
      int lrow = wv * 32 + mi * 16 + quad * 4 + r;
#pragma unroll
      for (int di = 0; di < 4; ++di)
        Ps[lrow * 72 + di * 16 + l15] = (__bf16)(oacc[mi][di][r] * invl);
    }
  __syncthreads();
  unsigned char* aop = ao + (size_t)b * 524288 + h * 64;
#pragma unroll
  for (int u = 0; u < 4; ++u) {
    int idx = u * 256 + tid;
    int row = idx >> 3, col = (idx & 7) * 8;
    uint2 v8 = cvt8_bf16_fp8(*(uint4*)&Ps[row * 72 + col]);
    *(uint2*)(aop + (size_t)(q0 + row) * 512 + col) = v8;
  }
}

// ---------------------------------------------------------------------------
// Kernel 4: out projection (fp8: ao x16, wo x16 -> acc/256) + bias +
// residual, transposed coalesced fp32 store. Unchanged from v8.
// ---------------------------------------------------------------------------
__global__ __launch_bounds__(256) void gemm_out_kernel(
    const unsigned char* __restrict__ ao, const unsigned char* __restrict__ wo,
    const float* __restrict__ bo, const float* __restrict__ x,
    float* __restrict__ out) {
  __shared__ __align__(16) unsigned char As[128 * 64];
  __shared__ __align__(16) unsigned char Bs[64 * 64];
  __shared__ __align__(16) float ctile[32 * 132];
  int tid = threadIdx.x;
  int m0 = blockIdx.x * 128;
  int n0 = blockIdx.y * 64;
  int wave = tid >> 6, lane = tid & 63;
  int l15 = lane & 15, quad = lane >> 4;
  int wm = wave >> 1, wn = wave & 1;   // wave tile: 64m x 32n

  floatx4 acc[4][2];
#pragma unroll
  for (int mi = 0; mi < 4; ++mi)
#pragma unroll
    for (int ni = 0; ni < 2; ++ni) acc[mi][ni] = (floatx4){0.f, 0.f, 0.f, 0.f};

  const unsigned char* gA[2]; unsigned char* lA[2];
#pragma unroll
  for (int u = 0; u < 2; ++u) {
    int slot = u * 256 + tid;
    int r = slot >> 2, cs = slot & 3;
    int c = cs ^ swz_s(r);
    gA[u] = ao + (size_t)(m0 + r) * 512 + c * 16;
    lA[u] = As + slot * 16;
  }
  const unsigned char* gB1; unsigned char* lB1;
  {
    int r = tid >> 2, cs = tid & 3;
    int c = cs ^ swz_s(r);
    gB1 = wo + (size_t)(n0 + r) * 512 + c * 16;
    lB1 = Bs + tid * 16;
  }

  for (int k0 = 0; k0 < 512; k0 += 64) {
    async_cp16(gA[0] + k0, lA[0]);
    async_cp16(gA[1] + k0, lA[1]);
    async_cp16(gB1 + k0, lB1);
    __syncthreads();
#pragma unroll
    for (int kh = 0; kh < 2; ++kh) {
      long af[4], bfr[2];
#pragma unroll
      for (int mi = 0; mi < 4; ++mi)
        af[mi] = *(const long*)&As[frag_addr(wm * 64 + mi * 16 + l15, kh, quad)];
#pragma unroll
      for (int ni = 0; ni < 2; ++ni)
        bfr[ni] = *(const long*)&Bs[frag_addr(wn * 32 + ni * 16 + l15, kh, quad)];
#pragma unroll
      for (int mi = 0; mi < 4; ++mi)
#pragma unroll
        for (int ni = 0; ni < 2; ++ni)
          acc[mi][ni] = mfma_fp8(af[mi], bfr[ni], acc[mi][ni]);
    }
    __syncthreads();
  }

  int b = m0 >> 10, s0 = m0 & 1023;
  for (int cc = 0; cc < 2; ++cc) {
    __syncthreads();
    if (wn == cc) {
#pragma unroll
      for (int ni = 0; ni < 2; ++ni) {
        int nn = ni * 16 + l15;
        float bias = bo[n0 + cc * 32 + nn];
#pragma unroll
        for (int mi = 0; mi < 4; ++mi)
#pragma unroll
          for (int r = 0; r < 4; ++r)
            ctile[nn * 132 + wm * 64 + mi * 16 + quad * 4 + r] =
                acc[mi][ni][r] * (1.f / 256.f) + bias;
      }
    }
    __syncthreads();
    int nn = tid >> 3, mlb = (tid & 7) * 16;
    int n = n0 + cc * 32 + nn;
    const float* xr = x + (size_t)(b * 512 + n) * 1024 + s0;
    float* orow = out + (size_t)(b * 512 + n) * 1024 + s0;
#pragma unroll
    for (int i = 0; i < 16; i += 4) {
      float4 cv = *(float4*)&ctile[nn * 132 + mlb + i];
      float4 xv = *(const float4*)&xr[mlb + i];
      float4 ov = {cv.x + xv.x, cv.y + xv.y, cv.z + xv.z, cv.w + xv.w};
      *(float4*)&orow[mlb + i] = ov;
    }
  }
}

// ---------------------------------------------------------------------------
extern "C" void kernel_launch(void* const* d_in, const int* in_sizes, int n_in,
                              void* d_out, int out_size, void* d_ws, size_t ws_size,
                              hipStream_t stream) {
  const float* x  = (const float*)d_in[0];
  const float* gs = (const float*)d_in[1];
  const float* gb = (const float*)d_in[2];
  const float* Wq = (const float*)d_in[3];
  const float* bq = (const float*)d_in[4];
  const float* Wk = (const float*)d_in[5];
  const float* bk = (const float*)d_in[6];
  const float* Wv = (const float*)d_in[7];
  const float* bv = (const float*)d_in[8];
  const float* Wo = (const float*)d_in[9];
  const float* bo = (const float*)d_in[10];
  float* out = (float*)d_out;

  char* ws = (char*)d_ws;
  unsigned char* wqkv = (unsigned char*)(ws);            //   786,432 fp8 x16
  unsigned char* wo   = (unsigned char*)(ws + 786432);   //   262,144 fp8 x16
  float* bqkv = (float*)(ws + 1048576);                  //     6,144
  unsigned char* t    = (unsigned char*)(ws + 1054720);  // 4,194,304 fp8 [b,s,c]
  unsigned char* ao   = t;                               // alias: t dead after QKV
  unsigned char* qb   = (unsigned char*)(ws + 5249024);  // 4,194,304 fp8 [b,h,s,d]
  unsigned char* kb   = (unsigned char*)(ws + 9443328);  // 4,194,304 fp8 [b,h,s,d]
  unsigned char* vtb  = (unsigned char*)(ws + 13637632); // 4,194,304 fp8 [b,h,d,s]

  prep_gn_kernel<<<dim3(512), dim3(256), 0, stream>>>(
      x, gs, gb, Wq, bq, Wk, bk, Wv, bv, Wo, wqkv, wo, bqkv, t);
  gemm_qkv_kernel<<<dim3(64, 12), dim3(256), 0, stream>>>(t, wqkv, bqkv, qb, kb, vtb);
  attn_kernel<<<dim3(512), dim3(256), 0, stream>>>(qb, kb, vtb, ao);
  gemm_out_kernel<<<dim3(64, 8), dim3(256), 0, stream>>>(ao, wo, bo, x, out);
}

// Round 10
// 144.019 us; speedup vs baseline: 1.0042x; 1.0042x over previous
//
#include <hip/hip_runtime.h>

// ---------------------------------------------------------------------------
// SelfAttentionBlock: GroupNorm(32,512) -> QKV(512x512) -> MHA(H=8,d=64,s=1024)
//                     -> out proj -> +residual.   b=8, x [8,512,32,32] fp32.
// v10 = v8 (revert of v9's MX-qkv experiment, which regressed: the qkv GEMM
// is latency/occupancy-bound at K=512, not MFMA-bound; MX K=128 cost LDS
// occupancy 10->5 blocks/CU and 64 live frag VGPRs for zero MFMA benefit).
// Full-fp8 data path: weights x16 fp8, q/k/v unscaled fp8, attention scale
// at exp2, ao x16 fp8; gn single-pass; l via VALU accumulate.
// ---------------------------------------------------------------------------

typedef __bf16 bf16x8 __attribute__((ext_vector_type(8)));
typedef __bf16 bf16x4 __attribute__((ext_vector_type(4)));
typedef float floatx4 __attribute__((ext_vector_type(4)));

static __device__ __forceinline__ floatx4 mfma_fp8(long a, long b, floatx4 c) {
  return __builtin_amdgcn_mfma_f32_16x16x32_fp8_fp8(a, b, c, 0, 0, 0);
}

// async global->LDS 16B DMA; LDS dest must be wave-uniform base + lane*16.
static __device__ __forceinline__ void async_cp16(const void* g, void* l) {
  __builtin_amdgcn_global_load_lds(
      (const __attribute__((address_space(1))) unsigned int*)g,
      (__attribute__((address_space(3))) unsigned int*)l, 16, 0, 0);
}

// 8 bf16 (uint4) -> 8 fp8 e4m3 (uint2)
static __device__ __forceinline__ uint2 cvt8_bf16_fp8(uint4 v) {
  union { uint4 u; __bf16 h[8]; } in; in.u = v;
  float f[8];
#pragma unroll
  for (int i = 0; i < 8; ++i) f[i] = (float)in.h[i];
  int lo = __builtin_amdgcn_cvt_pk_fp8_f32(f[0], f[1], 0, false);
  lo = __builtin_amdgcn_cvt_pk_fp8_f32(f[2], f[3], lo, true);
  int hi = __builtin_amdgcn_cvt_pk_fp8_f32(f[4], f[5], 0, false);
  hi = __builtin_amdgcn_cvt_pk_fp8_f32(f[6], f[7], hi, true);
  return uint2{(unsigned)lo, (unsigned)hi};
}

// fp8 LDS tile addressing: 64B rows, 16B chunks XOR-swizzled by
// s(r)=(r&3)^((r>>2)&3).
static __device__ __forceinline__ int swz_s(int r) {
  return (r & 3) ^ ((r >> 2) & 3);
}
static __device__ __forceinline__ int frag_addr(int row, int kh, int quad) {
  int chunk = (kh << 1) | (quad >> 1);
  return row * 64 + ((chunk ^ swz_s(row)) << 4) + ((quad & 1) << 3);
}

// ---------------------------------------------------------------------------
// Kernel 1: fused GroupNorm (blocks 0..255, single-pass) + weight prep
// (blocks 256..511). gn: x read once into regs; normalize + transpose to
// t[b,s,c] fp8. prep: wqkv/wo stored x16 fp8 (subnormal avoidance).
// ---------------------------------------------------------------------------
__global__ __launch_bounds__(256) void prep_gn_kernel(
    const float* __restrict__ x, const float* __restrict__ gamma,
    const float* __restrict__ beta,
    const float* __restrict__ Wq, const float* __restrict__ bq,
    const float* __restrict__ Wk, const float* __restrict__ bk,
    const float* __restrict__ Wv, const float* __restrict__ bv,
    const float* __restrict__ Wo,
    unsigned char* __restrict__ wqkv, unsigned char* __restrict__ wo,
    float* __restrict__ bqkv, unsigned char* __restrict__ t) {
  __shared__ __bf16 tile[16 * 1024];
  __shared__ float rbuf[8];
  int tid = threadIdx.x;
  int bx = blockIdx.x;

  if (bx >= 256) {
    int i = ((bx - 256) * 256 + tid) * 4;
    float4 q4 = *(const float4*)(Wq + i);
    float4 k4 = *(const float4*)(Wk + i);
    float4 v4 = *(const float4*)(Wv + i);
    float4 o4 = *(const float4*)(Wo + i);
    int p;
    p = __builtin_amdgcn_cvt_pk_fp8_f32(q4.x * 16.f, q4.y * 16.f, 0, false);
    p = __builtin_amdgcn_cvt_pk_fp8_f32(q4.z * 16.f, q4.w * 16.f, p, true);
    *(unsigned int*)(wqkv + i) = (unsigned)p;
    p = __builtin_amdgcn_cvt_pk_fp8_f32(k4.x * 16.f, k4.y * 16.f, 0, false);
    p = __builtin_amdgcn_cvt_pk_fp8_f32(k4.z * 16.f, k4.w * 16.f, p, true);
    *(unsigned int*)(wqkv + 262144 + i) = (unsigned)p;
    p = __builtin_amdgcn_cvt_pk_fp8_f32(v4.x * 16.f, v4.y * 16.f, 0, false);
    p = __builtin_amdgcn_cvt_pk_fp8_f32(v4.z * 16.f, v4.w * 16.f, p, true);
    *(unsigned int*)(wqkv + 524288 + i) = (unsigned)p;
    p = __builtin_amdgcn_cvt_pk_fp8_f32(o4.x * 16.f, o4.y * 16.f, 0, false);
    p = __builtin_amdgcn_cvt_pk_fp8_f32(o4.z * 16.f, o4.w * 16.f, p, true);
    *(unsigned int*)(wo + i) = (unsigned)p;
    int j = (bx - 256) * 256 + tid;
    if (j < 512) {
      bqkv[j]        = bq[j];
      bqkv[512 + j]  = bk[j];
      bqkv[1024 + j] = bv[j];
    }
    return;
  }

  int b = bx >> 5, g = bx & 31;
  const float4* xp4 = (const float4*)(x + (size_t)(b * 512 + g * 16) * 1024);

  // single pass: keep all 16 float4 (64 VGPRs) live across the reduction
  float4 vreg[16];
  float sacc = 0.f, ssacc = 0.f;
#pragma unroll
  for (int it = 0; it < 16; ++it) {
    float4 v = xp4[it * 256 + tid];
    vreg[it] = v;
    sacc += v.x + v.y + v.z + v.w;
    ssacc += v.x * v.x + v.y * v.y + v.z * v.z + v.w * v.w;
  }
#pragma unroll
  for (int off = 1; off < 64; off <<= 1) {
    sacc += __shfl_xor(sacc, off);
    ssacc += __shfl_xor(ssacc, off);
  }
  int wv = tid >> 6;
  if ((tid & 63) == 0) { rbuf[wv] = sacc; rbuf[4 + wv] = ssacc; }
  __syncthreads();
  float S1 = rbuf[0] + rbuf[1] + rbuf[2] + rbuf[3];
  float S2 = rbuf[4] + rbuf[5] + rbuf[6] + rbuf[7];
  float mean = S1 * (1.f / 16384.f);
  float var = S2 * (1.f / 16384.f) - mean * mean;
  float inv = rsqrtf(var + 1e-5f);

#pragma unroll
  for (int it = 0; it < 16; ++it) {
    float4 v = vreg[it];
    float ga = gamma[g * 16 + it], be = beta[g * 16 + it];
    int base = it * 1024 + tid * 4;
    tile[base + 0] = (__bf16)((v.x - mean) * inv * ga + be);
    tile[base + 1] = (__bf16)((v.y - mean) * inv * ga + be);
    tile[base + 2] = (__bf16)((v.z - mean) * inv * ga + be);
    tile[base + 3] = (__bf16)((v.w - mean) * inv * ga + be);
  }
  __syncthreads();

  // transposed fp8 write: t[(b*1024+s)*512 + g*16 + half*8], 8B stores
#pragma unroll
  for (int j = 0; j < 8; ++j) {
    int qid = j * 256 + tid;
    int sidx = qid >> 1, half = qid & 1;
    union { uint4 u; __bf16 h[8]; } o;
#pragma unroll
    for (int i = 0; i < 8; ++i) o.h[i] = tile[(half * 8 + i) * 1024 + sidx];
    uint2 v8 = cvt8_bf16_fp8(o.u);
    *(uint2*)(t + (size_t)(b * 1024 + sidx) * 512 + g * 16 + half * 8) = v8;
  }
}

// ---------------------------------------------------------------------------
// Kernel 2: fused QKV GEMM, full fp8. C[m,n] = t[m,:].wqkv[n,:]/16 + bias.
// M=8192, N=1536, K=512. 128x128 tile, 4 waves of 64x64, BK=64, swizzled
// global_load_lds staging, fp8 MFMA. Epilogue -> fp8 q,k [b,h,s,d];
// v -> transposed fp8 [b,h,d,s].
// ---------------------------------------------------------------------------
__global__ __launch_bounds__(256) void gemm_qkv_kernel(
    const unsigned char* __restrict__ t, const unsigned char* __restrict__ wqkv,
    const float* __restrict__ bqkv,
    unsigned char* __restrict__ qb, unsigned char* __restrict__ kb,
    unsigned char* __restrict__ vt) {
  __shared__ __align__(16) unsigned char smemraw[16384];  // As|Bs; epi ctile
  unsigned char* As = smemraw;
  unsigned char* Bs = smemraw + 8192;
  __bf16* ctile = (__bf16*)smemraw;    // 32 x 136 bf16 epilogue view
  int tid = threadIdx.x;
  int m0 = blockIdx.x * 128;
  int n0 = blockIdx.y * 128;
  int wave = tid >> 6, lane = tid & 63;
  int l15 = lane & 15, quad = lane >> 4;
  int wm = wave >> 1, wn = wave & 1;

  floatx4 acc[4][4];
#pragma unroll
  for (int mi = 0; mi < 4; ++mi)
#pragma unroll
    for (int ni = 0; ni < 4; ++ni) acc[mi][ni] = (floatx4){0.f, 0.f, 0.f, 0.f};

  const unsigned char* gA[2]; const unsigned char* gB[2];
  unsigned char *lA[2], *lB[2];
#pragma unroll
  for (int u = 0; u < 2; ++u) {
    int slot = u * 256 + tid;
    int r = slot >> 2, cs = slot & 3;
    int c = cs ^ swz_s(r);
    gA[u] = t + (size_t)(m0 + r) * 512 + c * 16;
    gB[u] = wqkv + (size_t)(n0 + r) * 512 + c * 16;
    lA[u] = As + slot * 16;
    lB[u] = Bs + slot * 16;
  }

  for (int k0 = 0; k0 < 512; k0 += 64) {
    async_cp16(gA[0] + k0, lA[0]);
    async_cp16(gA[1] + k0, lA[1]);
    async_cp16(gB[0] + k0, lB[0]);
    async_cp16(gB[1] + k0, lB[1]);
    __syncthreads();
#pragma unroll
    for (int kh = 0; kh < 2; ++kh) {
      long af[4], bfr[4];
#pragma unroll
      for (int mi = 0; mi < 4; ++mi)
        af[mi] = *(const long*)&As[frag_addr(wm * 64 + mi * 16 + l15, kh, quad)];
#pragma unroll
      for (int ni = 0; ni < 4; ++ni)
        bfr[ni] = *(const long*)&Bs[frag_addr(wn * 64 + ni * 16 + l15, kh, quad)];
#pragma unroll
      for (int mi = 0; mi < 4; ++mi)
#pragma unroll
        for (int ni = 0; ni < 4; ++ni)
          acc[mi][ni] = mfma_fp8(af[mi], bfr[ni], acc[mi][ni]);
    }
    __syncthreads();
  }

  int mat = n0 >> 9;           // 0=q, 1=k, 2=v
  int bidx = m0 >> 10, s0 = m0 & 1023;
  int hA = (n0 & 511) >> 6;
  float bias[4];
#pragma unroll
  for (int ni = 0; ni < 4; ++ni)
    bias[ni] = bqkv[n0 + wn * 64 + ni * 16 + l15];

  if (mat < 2) {
    unsigned char* dst = (mat == 0) ? qb : kb;
    for (int c = 0; c < 4; ++c) {
      if ((c >> 1) == wm) {
#pragma unroll
        for (int mi2 = 0; mi2 < 2; ++mi2) {
          int mi = (c & 1) * 2 + mi2;
          int lrow = mi2 * 16 + quad * 4;
#pragma unroll
          for (int ni = 0; ni < 4; ++ni)
#pragma unroll
            for (int r = 0; r < 4; ++r)
              ctile[(lrow + r) * 136 + wn * 64 + ni * 16 + l15] =
                  (__bf16)(acc[mi][ni][r] * 0.0625f + bias[ni]);
        }
      }
      __syncthreads();
#pragma unroll
      for (int u = 0; u < 2; ++u) {
        int f = tid * 16 + u * 8;
        int row = f >> 7, col = f & 127;
        uint2 val = cvt8_bf16_fp8(*(uint4*)&ctile[row * 136 + col]);
        int head = hA + (col >> 6), d = col & 63;
        *(uint2*)(dst + ((size_t)(bidx * 8 + head) * 1024 + s0 + c * 32 + row) * 64 + d) = val;
      }
      __syncthreads();
    }
  } else {
    for (int c = 0; c < 4; ++c) {
      if ((c >> 1) == wn) {
#pragma unroll
        for (int ni2 = 0; ni2 < 2; ++ni2) {
          int ni = (c & 1) * 2 + ni2;
          int nrow = ni2 * 16 + l15;
#pragma unroll
          for (int mi = 0; mi < 4; ++mi)
#pragma unroll
            for (int r = 0; r < 4; ++r)
              ctile[nrow * 136 + wm * 64 + mi * 16 + quad * 4 + r] =
                  (__bf16)(acc[mi][ni][r] * 0.0625f + bias[ni]);
        }
      }
      __syncthreads();
#pragma unroll
      for (int u = 0; u < 2; ++u) {
        int f = tid * 16 + u * 8;
        int nrow = f >> 7, mcol = f & 127;
        uint2 val = cvt8_bf16_fp8(*(uint4*)&ctile[nrow * 136 + mcol]);
        int nloc = c * 32 + nrow;
        int head = hA + (nloc >> 6), d = nloc & 63;
        *(uint2*)(vt + ((size_t)(bidx * 8 + head) * 64 + d) * 1024 + s0 + mcol) = val;
      }
      __syncthreads();
    }
  }
}

// ---------------------------------------------------------------------------
// Kernel 3: flash attention (fp8 core). Grid 512 = (b, h, q-tile of 128).
// 4 waves x 32 q-rows. S^T = mfma_fp8(K, Q); P = exp2(S*SCL) packed fp8.
// l accumulated in VALU regs, reduced post-loop, realigned via LDS.
// dbuf K/V (80B rows), 1 barrier/iter. ao stored x16 fp8.
// ---------------------------------------------------------------------------
__global__ __launch_bounds__(256) void attn_kernel(
    const unsigned char* __restrict__ qb, const unsigned char* __restrict__ kb,
    const unsigned char* __restrict__ vt, unsigned char* __restrict__ ao) {
  __shared__ __align__(16) unsigned char Ks[2][64 * 80];
  __shared__ __align__(16) unsigned char Vs[2][64 * 80];
  __shared__ __align__(16) __bf16 Ps[128 * 72];   // fp8 P / bf16 O epilogue
  __shared__ float lbuf[128];
  unsigned char* Psb = (unsigned char*)Ps;
  const float SCL = 0.125f * 1.4426950408889634f;
  int tid = threadIdx.x;
  int bx = blockIdx.x;
  int b = bx >> 6, h = (bx >> 3) & 7, q128 = bx & 7;
  int wv = tid >> 6, lane = tid & 63, l15 = lane & 15, quad = lane >> 4;
  size_t bh = (size_t)(b * 8 + h) * 65536;
  const unsigned char* Qp = qb + bh;
  const unsigned char* Kp = kb + bh;
  const unsigned char* Vp = vt + bh;   // [d][s], row stride 1024 bytes
  int q0 = q128 * 128, qw = q0 + wv * 32;

  long aq[2][2];
#pragma unroll
  for (int mi = 0; mi < 2; ++mi)
#pragma unroll
    for (int kh = 0; kh < 2; ++kh)
      aq[mi][kh] = *(const long*)(Qp + (size_t)(qw + mi * 16 + l15) * 64 + kh * 32 + quad * 8);

  floatx4 oacc[2][4];
  float lsum[2] = {0.f, 0.f};          // partial l for q = l15 (+16*mi)
#pragma unroll
  for (int mi = 0; mi < 2; ++mi)
#pragma unroll
    for (int di = 0; di < 4; ++di) oacc[mi][di] = (floatx4){0.f, 0.f, 0.f, 0.f};

  int srow = tid >> 2, scol = (tid & 3) * 16;
  int ldsoff = srow * 80 + scol;

  uint4 kr, vr;
  kr = *(const uint4*)(Kp + (size_t)srow * 64 + scol);
  vr = *(const uint4*)(Vp + (size_t)srow * 1024 + scol);

  for (int kt = 0; kt < 16; ++kt) {
    int cur = kt & 1;
    *(uint4*)&Ks[cur][ldsoff] = kr;
    *(uint4*)&Vs[cur][ldsoff] = vr;
    if (kt < 15) {
      int nt = kt + 1;
      kr = *(const uint4*)(Kp + (size_t)(nt * 64 + srow) * 64 + scol);
      vr = *(const uint4*)(Vp + (size_t)srow * 1024 + nt * 64 + scol);
    }
    __syncthreads();

    floatx4 sa[2][4];
#pragma unroll
    for (int ni = 0; ni < 4; ++ni) {
      long bk0 = *(const long*)&Ks[cur][(ni * 16 + l15) * 80 + quad * 8];
      long bk1 = *(const long*)&Ks[cur][(ni * 16 + l15) * 80 + 32 + quad * 8];
#pragma unroll
      for (int mi = 0; mi < 2; ++mi) {
        floatx4 s4 = (floatx4){0.f, 0.f, 0.f, 0.f};
        s4 = mfma_fp8(bk0, aq[mi][0], s4);
        s4 = mfma_fp8(bk1, aq[mi][1], s4);
        sa[mi][ni] = s4;
      }
    }

#pragma unroll
    for (int mi = 0; mi < 2; ++mi)
#pragma unroll
      for (int ni = 0; ni < 4; ++ni) {
        float e0 = __builtin_amdgcn_exp2f(sa[mi][ni][0] * SCL);
        float e1 = __builtin_amdgcn_exp2f(sa[mi][ni][1] * SCL);
        float e2 = __builtin_amdgcn_exp2f(sa[mi][ni][2] * SCL);
        float e3 = __builtin_amdgcn_exp2f(sa[mi][ni][3] * SCL);
        lsum[mi] += (e0 + e1) + (e2 + e3);
        int pk = __builtin_amdgcn_cvt_pk_fp8_f32(e0, e1, 0, false);
        pk = __builtin_amdgcn_cvt_pk_fp8_f32(e2, e3, pk, true);
        *(unsigned int*)&Psb[(wv * 32 + mi * 16 + l15) * 72 + ni * 16 + quad * 4] =
            (unsigned)pk;
      }

    long ap[2][2];
#pragma unroll
    for (int mi = 0; mi < 2; ++mi) {
      ap[mi][0] = *(const long*)&Psb[(wv * 32 + mi * 16 + l15) * 72 + quad * 8];
      ap[mi][1] = *(const long*)&Psb[(wv * 32 + mi * 16 + l15) * 72 + 32 + quad * 8];
    }
#pragma unroll
    for (int di = 0; di < 4; ++di) {
      long bv0 = *(const long*)&Vs[cur][(di * 16 + l15) * 80 + quad * 8];
      long bv1 = *(const long*)&Vs[cur][(di * 16 + l15) * 80 + 32 + quad * 8];
#pragma unroll
      for (int mi = 0; mi < 2; ++mi) {
        oacc[mi][di] = mfma_fp8(ap[mi][0], bv0, oacc[mi][di]);
        oacc[mi][di] = mfma_fp8(ap[mi][1], bv1, oacc[mi][di]);
      }
    }
  }

  // finalize l: sum the 4 quad-lanes sharing l15, stash to lbuf, realign.
#pragma unroll
  for (int mi = 0; mi < 2; ++mi) {
    lsum[mi] += __shfl_xor(lsum[mi], 16);
    lsum[mi] += __shfl_xor(lsum[mi], 32);
  }
  __syncthreads();   // waves done with fp8 P before overwriting Ps as bf16
  if (quad == 0) {
    lbuf[wv * 32 + l15] = lsum[0];
    lbuf[wv * 32 + 16 + l15] = lsum[1];
  }
  __syncthreads();

  // epilogue: O*16/l -> Ps (bf16 [128][72]) -> fp8 coalesced stores
#pragma unroll
  for (int mi = 0; mi < 2; ++mi)
#pragma unroll
    for (int r = 0; r < 4; ++r) {
      float invl = 16.f / lbuf[wv * 32 + mi * 16 + quad * 4 + r];
      int lrow = wv * 32 + mi * 16 + quad * 4 + r;
#pragma unroll
      for (int di = 0; di < 4; ++di)
        Ps[lrow * 72 + di * 16 + l15] = (__bf16)(oacc[mi][di][r] * invl);
    }
  __syncthreads();
  unsigned char* aop = ao + (size_t)b * 524288 + h * 64;
#pragma unroll
  for (int u = 0; u < 4; ++u) {
    int idx = u * 256 + tid;
    int row = idx >> 3, col = (idx & 7) * 8;
    uint2 v8 = cvt8_bf16_fp8(*(uint4*)&Ps[row * 72 + col]);
    *(uint2*)(aop + (size_t)(q0 + row) * 512 + col) = v8;
  }
}

// ---------------------------------------------------------------------------
// Kernel 4: out projection (fp8: ao x16, wo x16 -> acc/256) + bias +
// residual, transposed coalesced fp32 store. BN=64, BK=64 swizzled staging.
// ---------------------------------------------------------------------------
__global__ __launch_bounds__(256) void gemm_out_kernel(
    const unsigned char* __restrict__ ao, const unsigned char* __restrict__ wo,
    const float* __restrict__ bo, const float* __restrict__ x,
    float* __restrict__ out) {
  __shared__ __align__(16) unsigned char As[128 * 64];
  __shared__ __align__(16) unsigned char Bs[64 * 64];
  __shared__ __align__(16) float ctile[32 * 132];
  int tid = threadIdx.x;
  int m0 = blockIdx.x * 128;
  int n0 = blockIdx.y * 64;
  int wave = tid >> 6, lane = tid & 63;
  int l15 = lane & 15, quad = lane >> 4;
  int wm = wave >> 1, wn = wave & 1;   // wave tile: 64m x 32n

  floatx4 acc[4][2];
#pragma unroll
  for (int mi = 0; mi < 4; ++mi)
#pragma unroll
    for (int ni = 0; ni < 2; ++ni) acc[mi][ni] = (floatx4){0.f, 0.f, 0.f, 0.f};

  const unsigned char* gA[2]; unsigned char* lA[2];
#pragma unroll
  for (int u = 0; u < 2; ++u) {
    int slot = u * 256 + tid;
    int r = slot >> 2, cs = slot & 3;
    int c = cs ^ swz_s(r);
    gA[u] = ao + (size_t)(m0 + r) * 512 + c * 16;
    lA[u] = As + slot * 16;
  }
  const unsigned char* gB1; unsigned char* lB1;
  {
    int r = tid >> 2, cs = tid & 3;
    int c = cs ^ swz_s(r);
    gB1 = wo + (size_t)(n0 + r) * 512 + c * 16;
    lB1 = Bs + tid * 16;
  }

  for (int k0 = 0; k0 < 512; k0 += 64) {
    async_cp16(gA[0] + k0, lA[0]);
    async_cp16(gA[1] + k0, lA[1]);
    async_cp16(gB1 + k0, lB1);
    __syncthreads();
#pragma unroll
    for (int kh = 0; kh < 2; ++kh) {
      long af[4], bfr[2];
#pragma unroll
      for (int mi = 0; mi < 4; ++mi)
        af[mi] = *(const long*)&As[frag_addr(wm * 64 + mi * 16 + l15, kh, quad)];
#pragma unroll
      for (int ni = 0; ni < 2; ++ni)
        bfr[ni] = *(const long*)&Bs[frag_addr(wn * 32 + ni * 16 + l15, kh, quad)];
#pragma unroll
      for (int mi = 0; mi < 4; ++mi)
#pragma unroll
        for (int ni = 0; ni < 2; ++ni)
          acc[mi][ni] = mfma_fp8(af[mi], bfr[ni], acc[mi][ni]);
    }
    __syncthreads();
  }

  int b = m0 >> 10, s0 = m0 & 1023;
  for (int cc = 0; cc < 2; ++cc) {
    __syncthreads();
    if (wn == cc) {
#pragma unroll
      for (int ni = 0; ni < 2; ++ni) {
        int nn = ni * 16 + l15;
        float bias = bo[n0 + cc * 32 + nn];
#pragma unroll
        for (int mi = 0; mi < 4; ++mi)
#pragma unroll
          for (int r = 0; r < 4; ++r)
            ctile[nn * 132 + wm * 64 + mi * 16 + quad * 4 + r] =
                acc[mi][ni][r] * (1.f / 256.f) + bias;
      }
    }
    __syncthreads();
    int nn = tid >> 3, mlb = (tid & 7) * 16;
    int n = n0 + cc * 32 + nn;
    const float* xr = x + (size_t)(b * 512 + n) * 1024 + s0;
    float* orow = out + (size_t)(b * 512 + n) * 1024 + s0;
#pragma unroll
    for (int i = 0; i < 16; i += 4) {
      float4 cv = *(float4*)&ctile[nn * 132 + mlb + i];
      float4 xv = *(const float4*)&xr[mlb + i];
      float4 ov = {cv.x + xv.x, cv.y + xv.y, cv.z + xv.z, cv.w + xv.w};
      *(float4*)&orow[mlb + i] = ov;
    }
  }
}

// ---------------------------------------------------------------------------
extern "C" void kernel_launch(void* const* d_in, const int* in_sizes, int n_in,
                              void* d_out, int out_size, void* d_ws, size_t ws_size,
                              hipStream_t stream) {
  const float* x  = (const float*)d_in[0];
  const float* gs = (const float*)d_in[1];
  const float* gb = (const float*)d_in[2];
  const float* Wq = (const float*)d_in[3];
  const float* bq = (const float*)d_in[4];
  const float* Wk = (const float*)d_in[5];
  const float* bk = (const float*)d_in[6];
  const float* Wv = (const float*)d_in[7];
  const float* bv = (const float*)d_in[8];
  const float* Wo = (const float*)d_in[9];
  const float* bo = (const float*)d_in[10];
  float* out = (float*)d_out;

  char* ws = (char*)d_ws;
  unsigned char* wqkv = (unsigned char*)(ws);            //   786,432 fp8 x16
  unsigned char* wo   = (unsigned char*)(ws + 786432);   //   262,144 fp8 x16
  float* bqkv = (float*)(ws + 1048576);                  //     6,144
  unsigned char* t    = (unsigned char*)(ws + 1054720);  // 4,194,304 fp8 [b,s,c]
  unsigned char* ao   = t;                               // alias: t dead after QKV
  unsigned char* qb   = (unsigned char*)(ws + 5249024);  // 4,194,304 fp8 [b,h,s,d]
  unsigned char* kb   = (unsigned char*)(ws + 9443328);  // 4,194,304 fp8 [b,h,s,d]
  unsigned char* vtb  = (unsigned char*)(ws + 13637632); // 4,194,304 fp8 [b,h,d,s]

  prep_gn_kernel<<<dim3(512), dim3(256), 0, stream>>>(
      x, gs, gb, Wq, bq, Wk, bk, Wv, bv, Wo, wqkv, wo, bqkv, t);
  gemm_qkv_kernel<<<dim3(64, 12), dim3(256), 0, stream>>>(t, wqkv, bqkv, qb, kb, vtb);
  attn_kernel<<<dim3(512), dim3(256), 0, stream>>>(qb, kb, vtb, ao);
  gemm_out_kernel<<<dim3(64, 8), dim3(256), 0, stream>>>(ao, wo, bo, x, out);
}